// Round 3
// baseline (1155.096 us; speedup 1.0000x reference)
//
#include <hip/hip_runtime.h>

typedef __attribute__((ext_vector_type(4))) float f4;
typedef __attribute__((ext_vector_type(8))) short bfx8;
typedef __attribute__((ext_vector_type(4))) float f32x4;
typedef __attribute__((ext_vector_type(4))) unsigned int u32x4;
typedef __attribute__((ext_vector_type(4))) unsigned short u16x4;
typedef unsigned short ushort_t;

#define DM 768
#define DINNER 1536
#define NH 24
#define CONVCH 1664
#define DINPROJ 3224
#define NPAD1 3328
#define NCHUNK 64
#define BROWS 8192

__device__ inline ushort_t f2bf(float f) {
    unsigned u = __builtin_bit_cast(unsigned, f);
    unsigned r = (u + 0x7FFF + ((u >> 16) & 1)) >> 16;
    return (ushort_t)r;
}
__device__ inline float bf2f(ushort_t u) {
    return __builtin_bit_cast(float, (unsigned)u << 16);
}
__device__ inline u32x4 pack8(f4 a, f4 b) {
    u32x4 o;
    o[0] = (unsigned)f2bf(a[0]) | ((unsigned)f2bf(a[1]) << 16);
    o[1] = (unsigned)f2bf(a[2]) | ((unsigned)f2bf(a[3]) << 16);
    o[2] = (unsigned)f2bf(b[0]) | ((unsigned)f2bf(b[1]) << 16);
    o[3] = (unsigned)f2bf(b[2]) | ((unsigned)f2bf(b[3]) << 16);
    return o;
}

__global__ __launch_bounds__(256) void fill_kernel(float* out, int n, float v) {
    int i = blockIdx.x * 256 + threadIdx.x;
    if (i < n) out[i] = v;
}

// ---- GEMM C[M][ldc] = A[M][K] * B[N][K]^T. A: f32 or bf16; B: f32 (rows >= nrowsB are zero) ----
template <bool AF32>
__global__ __launch_bounds__(256) void gemm_bt(const void* __restrict__ Ap,
                                               const float* __restrict__ B,
                                               float* __restrict__ C,
                                               int M, int K, int ldc, int nvalid, int nrowsB) {
    __shared__ __align__(16) ushort_t As[128 * 32];
    __shared__ __align__(16) ushort_t Bs[128 * 32];
    int tid = threadIdx.x;
    int lane = tid & 63;
    int w = tid >> 6;
    int wr = w >> 1, wc = w & 1;
    int m0 = blockIdx.y * 128;
    int n0 = blockIdx.x * 128;
    int r16 = lane & 15, kg = lane >> 4;

    f32x4 acc[4][4] = {};

    for (int k0 = 0; k0 < K; k0 += 32) {
        u32x4 av[2], bv[2];
#pragma unroll
        for (int r = 0; r < 2; ++r) {
            int chunk = tid + 256 * r;
            int row = chunk >> 2, cof = (chunk & 3) * 8;
            if (AF32) {
                const float* A = (const float*)Ap;
                f4 a0 = *(const f4*)&A[(long)(m0 + row) * K + k0 + cof];
                f4 a1 = *(const f4*)&A[(long)(m0 + row) * K + k0 + cof + 4];
                av[r] = pack8(a0, a1);
            } else {
                const ushort_t* A = (const ushort_t*)Ap;
                av[r] = *(const u32x4*)&A[(long)(m0 + row) * K + k0 + cof];
            }
            int br = n0 + row;
            if (br < nrowsB) {
                f4 b0 = *(const f4*)&B[(long)br * K + k0 + cof];
                f4 b1 = *(const f4*)&B[(long)br * K + k0 + cof + 4];
                bv[r] = pack8(b0, b1);
            } else {
                bv[r] = (u32x4){0, 0, 0, 0};
            }
        }
        __syncthreads();
#pragma unroll
        for (int r = 0; r < 2; ++r) {
            int chunk = tid + 256 * r;
            int row = chunk >> 2, cof = (chunk & 3) * 8;
            *(u32x4*)&As[row * 32 + cof] = av[r];
            *(u32x4*)&Bs[row * 32 + cof] = bv[r];
        }
        __syncthreads();
        bfx8 af[4], bfr[4];
#pragma unroll
        for (int i = 0; i < 4; ++i) {
            af[i] = *(const bfx8*)&As[(wr * 64 + i * 16 + r16) * 32 + kg * 8];
            bfr[i] = *(const bfx8*)&Bs[(wc * 64 + i * 16 + r16) * 32 + kg * 8];
        }
#pragma unroll
        for (int i = 0; i < 4; ++i)
#pragma unroll
            for (int j = 0; j < 4; ++j)
                acc[i][j] = __builtin_amdgcn_mfma_f32_16x16x32_bf16(af[i], bfr[j], acc[i][j], 0, 0, 0);
    }

#pragma unroll
    for (int i = 0; i < 4; ++i) {
        int rowb = m0 + wr * 64 + i * 16 + kg * 4;
#pragma unroll
        for (int j = 0; j < 4; ++j) {
            int col = n0 + wc * 64 + j * 16 + r16;
            if (col < nvalid) {
#pragma unroll
                for (int q = 0; q < 4; ++q)
                    C[(long)(rowb + q) * ldc + col] = acc[i][j][q];
            }
        }
    }
}

// ---- dt = softplus(zx[..., 3200+h] + dt_bias) ----
__global__ __launch_bounds__(256) void dt_kernel(const float* __restrict__ zx,
                                                 const float* __restrict__ dt_bias,
                                                 float* __restrict__ dtb) {
    int i = blockIdx.x * 256 + threadIdx.x;
    if (i >= BROWS * NH) return;
    int row = i / NH, h = i % NH;
    float v = zx[(long)row * DINPROJ + DINNER + CONVCH + h] + dt_bias[h];
    float d = (v > 20.f) ? v : log1pf(__expf(v));
    dtb[row * NH + h] = d;
}

// ---- depthwise causal conv(4) + bias + silu ----
__global__ __launch_bounds__(256) void conv_kernel(const float* __restrict__ zx,
                                                   const float* __restrict__ cw,
                                                   const float* __restrict__ cb,
                                                   float* __restrict__ xbc) {
    int ch = blockIdx.y * 256 + threadIdx.x;
    int row = blockIdx.x;
    if (ch >= CONVCH) return;
    int b = row >> 12;
    int l = row & 4095;
    float acc = cb[ch];
#pragma unroll
    for (int k = 0; k < 4; ++k) {
        int ll = l - 3 + k;
        if (ll >= 0)
            acc += cw[ch * 4 + k] * zx[(long)(b * 4096 + ll) * DINPROJ + DINNER + ch];
    }
    float s = acc / (1.f + __expf(-acc));
    xbc[(long)row * CONVCH + ch] = s;
}

// ---- per-chunk cumsum of A*dt ----
__global__ __launch_bounds__(256) void acs_kernel(const float* __restrict__ dtb,
                                                  const float* __restrict__ A_log,
                                                  float* __restrict__ acs,
                                                  float* __restrict__ Tsum) {
    int i = blockIdx.x * 256 + threadIdx.x;
    if (i >= 2 * NH * NCHUNK) return;
    int c = i % NCHUNK;
    int bh = i / NCHUNK;
    int h = bh % NH;
    int b = bh / NH;
    float A = -__expf(A_log[h]);
    float s = 0.f;
    long base = ((long)(b * NH + h) * NCHUNK + c) * 64;
    for (int l = 0; l < 64; ++l) {
        s += A * dtb[(long)(b * 4096 + c * 64 + l) * NH + h];
        acs[base + l] = s;
    }
    Tsum[(b * NH + h) * NCHUNK + c] = s;
}

// ---- phase A: per-chunk states[p][n] -> bf16 ----
__global__ __launch_bounds__(256) void states_kernel(const float* __restrict__ xbc,
                                                     const float* __restrict__ dtb,
                                                     const float* __restrict__ acs,
                                                     const float* __restrict__ Tsum,
                                                     ushort_t* __restrict__ states) {
    int c = blockIdx.x, h = blockIdx.y, b = blockIdx.z;
    __shared__ __align__(16) float sW[64 * 64];
    __shared__ __align__(16) float sB[64 * 64];
    __shared__ float sDec[64];
    int t = threadIdx.x;
    long rowg0 = (long)b * 4096 + c * 64;
    long acsb = ((long)(b * NH + h) * NCHUNK + c) * 64;
    float T = Tsum[(b * NH + h) * NCHUNK + c];
    if (t < 64) sDec[t] = __expf(T - acs[acsb + t]);
    __syncthreads();
#pragma unroll
    for (int i = 0; i < 16; ++i) {
        int idx = t + 256 * i;
        int l = idx >> 6, col = idx & 63;
        long rg = rowg0 + l;
        sW[idx] = xbc[rg * CONVCH + h * 64 + col] * dtb[rg * NH + h] * sDec[l];
        sB[idx] = xbc[rg * CONVCH + DINNER + col];
    }
    __syncthreads();
    int p0 = (t >> 4) * 4, n0 = (t & 15) * 4;
    float acc[4][4] = {};
    for (int l = 0; l < 64; ++l) {
        f4 wv = *(const f4*)&sW[l * 64 + p0];
        f4 bv = *(const f4*)&sB[l * 64 + n0];
#pragma unroll
        for (int i = 0; i < 4; ++i)
#pragma unroll
            for (int j = 0; j < 4; ++j)
                acc[i][j] += wv[i] * bv[j];
    }
    long ob = ((long)(b * NH + h) * NCHUNK + c) * 4096;
#pragma unroll
    for (int i = 0; i < 4; ++i) {
        u16x4 o;
#pragma unroll
        for (int j = 0; j < 4; ++j) o[j] = f2bf(acc[i][j]);
        *(u16x4*)&states[ob + (p0 + i) * 64 + n0] = o;
    }
}

// ---- sequential chunk scan: states -> Sprev (in place, bf16 storage, f32 math) ----
__global__ __launch_bounds__(256) void scan_kernel(const float* __restrict__ Tsum,
                                                   ushort_t* __restrict__ states) {
    int e = blockIdx.x * 256 + threadIdx.x;  // 0..4095
    int h = blockIdx.y, b = blockIdx.z;
    long base = ((long)(b * NH + h)) * NCHUNK * 4096 + e;
    const float* Tp = &Tsum[(b * NH + h) * NCHUNK];
    float acc = 0.f;
    for (int c = 0; c < NCHUNK; ++c) {
        float cur = bf2f(states[base + (long)c * 4096]);
        states[base + (long)c * 4096] = f2bf(acc);
        acc = __expf(Tp[c]) * acc + cur;
    }
}

// ---- phase C: Y = (CB^T . Lm) @ xd + expAcs * (C @ Sprev^T); y -> zx cols [1536,3072) ----
__global__ __launch_bounds__(256) void yfull_kernel(const float* __restrict__ xbc,
                                                    const float* __restrict__ dtb,
                                                    const float* __restrict__ acs,
                                                    const ushort_t* __restrict__ sprev,
                                                    float* __restrict__ zx) {
    int c = blockIdx.x, h = blockIdx.y, b = blockIdx.z;
    __shared__ __align__(16) float bufC[64 * 64];
    __shared__ __align__(16) float bufB[64 * 64];  // B -> xd -> Sprev
    __shared__ __align__(16) float bufS[64 * 64];
    __shared__ float sAcs[64], sE[64];
    int t = threadIdx.x;
    long rowg0 = (long)b * 4096 + c * 64;
    long acsb = ((long)(b * NH + h) * NCHUNK + c) * 64;
    if (t < 64) {
        float a = acs[acsb + t];
        sAcs[t] = a;
        sE[t] = __expf(a);
    }
#pragma unroll
    for (int i = 0; i < 16; ++i) {
        int idx = t + 256 * i;
        int l = idx >> 6, col = idx & 63;
        long rg = (rowg0 + l) * CONVCH;
        bufC[idx] = xbc[rg + DINNER + 64 + col];
        bufB[idx] = xbc[rg + DINNER + col];
    }
    __syncthreads();
    int l0 = (t >> 4) * 4, s0 = (t & 15) * 4;
    float sc[4][4] = {};
    for (int n = 0; n < 64; n += 4) {
        f4 cv[4], bv[4];
#pragma unroll
        for (int i = 0; i < 4; ++i) cv[i] = *(const f4*)&bufC[(l0 + i) * 64 + n];
#pragma unroll
        for (int j = 0; j < 4; ++j) bv[j] = *(const f4*)&bufB[(s0 + j) * 64 + n];
#pragma unroll
        for (int i = 0; i < 4; ++i)
#pragma unroll
            for (int j = 0; j < 4; ++j)
                sc[i][j] += cv[i][0] * bv[j][0] + cv[i][1] * bv[j][1] +
                            cv[i][2] * bv[j][2] + cv[i][3] * bv[j][3];
    }
    __syncthreads();  // all reads of B done
#pragma unroll
    for (int i = 0; i < 4; ++i) {
        f4 o;
#pragma unroll
        for (int j = 0; j < 4; ++j) {
            int l = l0 + i, s = s0 + j;
            o[j] = (s <= l) ? sc[i][j] * __expf(sAcs[l] - sAcs[s]) : 0.f;
        }
        *(f4*)&bufS[(l0 + i) * 64 + s0] = o;
    }
#pragma unroll
    for (int i = 0; i < 16; ++i) {
        int idx = t + 256 * i;
        int l = idx >> 6, col = idx & 63;
        long rg = rowg0 + l;
        bufB[idx] = xbc[rg * CONVCH + h * 64 + col] * dtb[rg * NH + h];  // xd
    }
    __syncthreads();
    int p0 = s0;
    float yd[4][4] = {};
    for (int s = 0; s < 64; s += 4) {
        f4 sv[4];
#pragma unroll
        for (int i = 0; i < 4; ++i) sv[i] = *(const f4*)&bufS[(l0 + i) * 64 + s];
        f4 x0 = *(const f4*)&bufB[(s + 0) * 64 + p0];
        f4 x1 = *(const f4*)&bufB[(s + 1) * 64 + p0];
        f4 x2 = *(const f4*)&bufB[(s + 2) * 64 + p0];
        f4 x3 = *(const f4*)&bufB[(s + 3) * 64 + p0];
#pragma unroll
        for (int i = 0; i < 4; ++i)
#pragma unroll
            for (int j = 0; j < 4; ++j)
                yd[i][j] += sv[i][0] * x0[j] + sv[i][1] * x1[j] + sv[i][2] * x2[j] + sv[i][3] * x3[j];
    }
    __syncthreads();  // done with xd
    long spb = ((long)(b * NH + h) * NCHUNK + c) * 4096;
#pragma unroll
    for (int i = 0; i < 16; ++i) {
        int idx = t + 256 * i;
        bufB[idx] = bf2f(sprev[spb + idx]);  // Sprev[p][n]
    }
    __syncthreads();
    float yo[4][4] = {};
    for (int n = 0; n < 64; n += 4) {
        f4 cv[4], pv[4];
#pragma unroll
        for (int i = 0; i < 4; ++i) cv[i] = *(const f4*)&bufC[(l0 + i) * 64 + n];
#pragma unroll
        for (int j = 0; j < 4; ++j) pv[j] = *(const f4*)&bufB[(p0 + j) * 64 + n];
#pragma unroll
        for (int i = 0; i < 4; ++i)
#pragma unroll
            for (int j = 0; j < 4; ++j)
                yo[i][j] += cv[i][0] * pv[j][0] + cv[i][1] * pv[j][1] +
                            cv[i][2] * pv[j][2] + cv[i][3] * pv[j][3];
    }
#pragma unroll
    for (int i = 0; i < 4; ++i) {
        f4 o;
#pragma unroll
        for (int j = 0; j < 4; ++j) o[j] = yd[i][j] + sE[l0 + i] * yo[i][j];
        *(f4*)&zx[(rowg0 + l0 + i) * DINPROJ + DINNER + h * 64 + p0] = o;
    }
}

// ---- gated RMS norm -> bf16 (y read from zx cols [1536,3072), z from cols [0,1536)) ----
__global__ __launch_bounds__(256) void norm_kernel(const float* __restrict__ zx,
                                                   const float* __restrict__ xbc,
                                                   const float* __restrict__ Dp,
                                                   const float* __restrict__ normw,
                                                   ushort_t* __restrict__ ybf) {
    int row = blockIdx.x;
    int t = threadIdx.x;
    float g[6];
    float ss = 0.f;
#pragma unroll
    for (int i = 0; i < 6; ++i) {
        int j = t + 256 * i;
        int h = j >> 6;
        float x = xbc[(long)row * CONVCH + j];
        float yy = zx[(long)row * DINPROJ + DINNER + j] + x * Dp[h];
        float z = zx[(long)row * DINPROJ + j];
        float gz = z / (1.f + __expf(-z));
        float v = yy * gz;
        g[i] = v;
        ss += v * v;
    }
#pragma unroll
    for (int o = 32; o > 0; o >>= 1) ss += __shfl_xor(ss, o, 64);
    __shared__ float wsum[4];
    __shared__ float sscale;
    int w = t >> 6;
    if ((t & 63) == 0) wsum[w] = ss;
    __syncthreads();
    if (t == 0) {
        float tot = wsum[0] + wsum[1] + wsum[2] + wsum[3];
        sscale = rsqrtf(tot / (float)DINNER + 1e-5f);
    }
    __syncthreads();
    float sc = sscale;
#pragma unroll
    for (int i = 0; i < 6; ++i) {
        int j = t + 256 * i;
        ybf[(long)row * DINNER + j] = f2bf(g[i] * sc * normw[j]);
    }
}

extern "C" void kernel_launch(void* const* d_in, const int* in_sizes, int n_in,
                              void* d_out, int out_size, void* d_ws, size_t ws_size,
                              hipStream_t stream) {
    const float* u = (const float*)d_in[0];
    const float* W_in = (const float*)d_in[1];
    const float* conv_w = (const float*)d_in[2];
    const float* conv_b = (const float*)d_in[3];
    const float* dt_bias = (const float*)d_in[4];
    const float* A_log = (const float*)d_in[5];
    const float* Dp = (const float*)d_in[6];
    const float* norm_w = (const float*)d_in[7];
    const float* W_out = (const float*)d_in[8];
    float* out = (float*)d_out;

    char* ws = (char*)d_ws;
    size_t off = 0;
    auto alloc = [&](size_t bytes) {
        void* p = ws + off;
        off += (bytes + 255) & ~(size_t)255;
        return p;
    };
    float* zx = (float*)alloc((size_t)BROWS * DINPROJ * 4);         // 105.6 MB (y reuses cols 1536..3072)
    float* xbc = (float*)alloc((size_t)BROWS * CONVCH * 4);         // 54.5 MB
    float* dtb = (float*)alloc((size_t)BROWS * NH * 4);             // 0.79 MB
    float* acs = (float*)alloc((size_t)2 * NH * NCHUNK * 64 * 4);   // 0.79 MB
    float* Tsum = (float*)alloc((size_t)2 * NH * NCHUNK * 4);       // 12 KB
    ushort_t* states = (ushort_t*)alloc((size_t)2 * NH * NCHUNK * 4096 * 2);  // 25.2 MB
    ushort_t* ybf = states;  // alias: ybf written only after yfull consumed states

    if (off > ws_size) {  // diagnostic: distinguish "ws too small" from "kernels wrong"
        fill_kernel<<<(out_size + 255) / 256, 256, 0, stream>>>(out, out_size, 12345.0f);
        return;
    }

    // in-projection: zx = u @ W_in^T   (f32 -> bf16 staged in-kernel)
    gemm_bt<true><<<dim3(NPAD1 / 128, BROWS / 128), 256, 0, stream>>>(
        u, W_in, zx, BROWS, DM, DINPROJ, DINPROJ, DINPROJ);

    // dt + conv
    dt_kernel<<<(BROWS * NH + 255) / 256, 256, 0, stream>>>(zx, dt_bias, dtb);
    conv_kernel<<<dim3(BROWS, (CONVCH + 255) / 256), 256, 0, stream>>>(zx, conv_w, conv_b, xbc);

    // SSD
    acs_kernel<<<(2 * NH * NCHUNK + 255) / 256, 256, 0, stream>>>(dtb, A_log, acs, Tsum);
    states_kernel<<<dim3(NCHUNK, NH, 2), 256, 0, stream>>>(xbc, dtb, acs, Tsum, states);
    scan_kernel<<<dim3(16, NH, 2), 256, 0, stream>>>(Tsum, states);
    yfull_kernel<<<dim3(NCHUNK, NH, 2), 256, 0, stream>>>(xbc, dtb, acs, states, zx);

    // gate + rmsnorm -> bf16
    norm_kernel<<<BROWS, 256, 0, stream>>>(zx, xbc, Dp, norm_w, ybf);

    // out-projection: out = ybf @ W_out^T
    gemm_bt<false><<<dim3(DM / 128, BROWS / 128), 256, 0, stream>>>(
        ybf, W_out, out, BROWS, DINNER, DM, DM, DM);
}